// Round 1
// baseline (657.386 us; speedup 1.0000x reference)
//
#include <hip/hip_runtime.h>
#include <math.h>

#define NB 64        // batch
#define IFD 1024     // in features
#define PP 128       // P (num keys)
#define PSD 2048     // PS0/PS1
#define PK 64        // PKEY
#define NFD 64       // NF
#define DELTAF 1e-6f

// ---------------------------------------------------------------------------
// Kernel 1: k = x @ W^T + b for 3 components.  C[m][n] = sum_k x[m][k]*W[n][k]
// M=64, N=4096, K=1024.  grid (N/64, 3), block 256, micro 4x4.
// ---------------------------------------------------------------------------
__global__ __launch_bounds__(256) void k_proj(
    const float* __restrict__ x,
    const float* __restrict__ Wu, const float* __restrict__ bu,
    const float* __restrict__ Wv, const float* __restrict__ bv,
    const float* __restrict__ Ws, const float* __restrict__ bs,
    float* __restrict__ ko)   // [3][64][4096]
{
    const int comp = blockIdx.y;
    const float* W    = comp == 0 ? Wu : (comp == 1 ? Wv : Ws);
    const float* bias = comp == 0 ? bu : (comp == 1 ? bv : bs);
    float* out = ko + (size_t)comp * NB * 4096;

    const int n0 = blockIdx.x * 64;
    __shared__ float xs[64][64];   // [k][m]
    __shared__ float ws_t[64][64]; // [k][n]
    const int t = threadIdx.x;
    const int tx = t & 15, ty = t >> 4;

    float acc[4][4] = {};

    for (int k0 = 0; k0 < IFD; k0 += 64) {
        #pragma unroll
        for (int pass = 0; pass < 4; ++pass) {
            const int row = pass * 16 + ty;
            const int c4 = tx * 4;
            float4 va = *(const float4*)&x[(size_t)row * IFD + k0 + c4];
            xs[c4 + 0][row] = va.x; xs[c4 + 1][row] = va.y;
            xs[c4 + 2][row] = va.z; xs[c4 + 3][row] = va.w;
            float4 vb = *(const float4*)&W[(size_t)(n0 + row) * IFD + k0 + c4];
            ws_t[c4 + 0][row] = vb.x; ws_t[c4 + 1][row] = vb.y;
            ws_t[c4 + 2][row] = vb.z; ws_t[c4 + 3][row] = vb.w;
        }
        __syncthreads();
        #pragma unroll 16
        for (int k = 0; k < 64; ++k) {
            float4 a4 = *(const float4*)&xs[k][ty * 4];
            float4 b4 = *(const float4*)&ws_t[k][tx * 4];
            float av[4] = {a4.x, a4.y, a4.z, a4.w};
            float bv4[4] = {b4.x, b4.y, b4.z, b4.w};
            #pragma unroll
            for (int i = 0; i < 4; ++i)
                #pragma unroll
                for (int j = 0; j < 4; ++j)
                    acc[i][j] += av[i] * bv4[j];
        }
        __syncthreads();
    }
    #pragma unroll
    for (int i = 0; i < 4; ++i) {
        const int m = ty * 4 + i;
        const int n = n0 + tx * 4;
        float4 o = make_float4(acc[i][0] + bias[n + 0], acc[i][1] + bias[n + 1],
                               acc[i][2] + bias[n + 2], acc[i][3] + bias[n + 3]);
        *(float4*)&out[(size_t)m * 4096 + n] = o;
    }
}

// ---------------------------------------------------------------------------
// Kernel 2a: a_n[comp][p] = ||MK_p|| + DELTA.  grid 3, block 128.
// ---------------------------------------------------------------------------
__global__ void k_norms(const float* __restrict__ PMU, const float* __restrict__ PMV,
                        const float* __restrict__ PMS, float* __restrict__ a_n)
{
    const int comp = blockIdx.x;
    const float* PM = comp == 0 ? PMU : (comp == 1 ? PMV : PMS);
    const int stride = (comp == 2) ? (PK + 1) : (PK + PSD);
    const int p = threadIdx.x;
    const float* row = PM + (size_t)p * stride;
    float ss = 0.f;
    #pragma unroll
    for (int k = 0; k < PK; ++k) { float v = row[k]; ss += v * v; }
    a_n[comp * PP + p] = sqrtf(ss) + DELTAF;
}

// ---------------------------------------------------------------------------
// Kernel 2b: theta + softmax.  grid (B*NF, 3), block 128 (one thread per p).
// d[b,f,p] = softmax_p( dot(MK_p, k_bf) / (64 * b_n * a_n[p] + DELTA) )
// ---------------------------------------------------------------------------
__global__ __launch_bounds__(128) void k_theta(
    const float* __restrict__ ko, const float* __restrict__ PMU,
    const float* __restrict__ PMV, const float* __restrict__ PMS,
    const float* __restrict__ a_n, float* __restrict__ dout)  // [3][4096][128]
{
    const int comp = blockIdx.y;
    const float* PM = comp == 0 ? PMU : (comp == 1 ? PMV : PMS);
    const int stride = (comp == 2) ? (PK + 1) : (PK + PSD);
    const float* krow = ko + (size_t)comp * NB * 4096 + (size_t)blockIdx.x * PK;
    float* drow = dout + (size_t)comp * 4096 * PP + (size_t)blockIdx.x * PP;

    __shared__ float kr[PK];
    __shared__ float mk[PP][PK + 1];
    __shared__ float smax[2], ssum[2];

    const int t = threadIdx.x;
    if (t < PK) kr[t] = krow[t];
    for (int idx = t; idx < PP * PK; idx += 128) {
        const int r = idx >> 6, c = idx & 63;
        mk[r][c] = PM[(size_t)r * stride + c];
    }
    __syncthreads();

    float ss = 0.f;
    #pragma unroll
    for (int k = 0; k < PK; ++k) ss += kr[k] * kr[k];
    const float b_n = sqrtf(ss) + DELTAF;

    const int p = t;
    float num = 0.f;
    #pragma unroll
    for (int k = 0; k < PK; ++k) num += mk[p][k] * kr[k];
    const float dval = num / (64.f * b_n * a_n[comp * PP + p] + DELTAF);

    // softmax over 128 threads (2 waves)
    float mx = dval;
    #pragma unroll
    for (int o = 32; o >= 1; o >>= 1) mx = fmaxf(mx, __shfl_xor(mx, o, 64));
    if ((t & 63) == 0) smax[t >> 6] = mx;
    __syncthreads();
    mx = fmaxf(smax[0], smax[1]);
    const float e = expf(dval - mx);
    float sm = e;
    #pragma unroll
    for (int o = 32; o >= 1; o >>= 1) sm += __shfl_xor(sm, o, 64);
    if ((t & 63) == 0) ssum[t >> 6] = sm;
    __syncthreads();
    sm = ssum[0] + ssum[1];
    drow[p] = e / sm;
}

// ---------------------------------------------------------------------------
// Kernel 3: s[b,f] = cumsum_f( softplus( d_s[b,f,:] . MP_S ) ).  grid 64, block 64.
// ---------------------------------------------------------------------------
__global__ void k_scan(const float* __restrict__ dout, const float* __restrict__ PMS,
                       float* __restrict__ sbuf)
{
    const int b = blockIdx.x, f = threadIdx.x;
    __shared__ float mp[PP];
    mp[f] = PMS[(size_t)f * (PK + 1) + PK];
    mp[f + 64] = PMS[(size_t)(f + 64) * (PK + 1) + PK];
    __syncthreads();
    const float* drow = dout + (size_t)2 * 4096 * PP + ((size_t)b * NFD + f) * PP;
    float v = 0.f;
    #pragma unroll
    for (int p = 0; p < PP; ++p) v += drow[p] * mp[p];
    float sp = (v > 20.f) ? v : log1pf(expf(v));
    #pragma unroll
    for (int o = 1; o < 64; o <<= 1) {
        float u = __shfl_up(sp, o, 64);
        if (f >= o) sp += u;
    }
    sbuf[b * NFD + f] = sp;
}

// ---------------------------------------------------------------------------
// Kernel 4: Us/Vs = d @ MP  (M=4096, K=128, N=2048); U scaled by s[m].
// grid (32, 64, 2), block 256, micro 4x4, BK=64.
// ---------------------------------------------------------------------------
__global__ __launch_bounds__(256) void k_mp(
    const float* __restrict__ dout, const float* __restrict__ PMU,
    const float* __restrict__ PMV, const float* __restrict__ sbuf,
    float* __restrict__ UsS, float* __restrict__ Vsb)
{
    const int comp = blockIdx.z;
    const float* A = dout + (size_t)comp * 4096 * PP;
    const float* PM = comp == 0 ? PMU : PMV;
    float* C = comp == 0 ? UsS : Vsb;
    const int n0 = blockIdx.x * 64, m0 = blockIdx.y * 64;

    __shared__ float As[64][64];  // [k][m]
    __shared__ float Bs[64][64];  // [k][n]
    const int t = threadIdx.x, tx = t & 15, ty = t >> 4;
    float acc[4][4] = {};

    for (int k0 = 0; k0 < PP; k0 += 64) {
        #pragma unroll
        for (int pass = 0; pass < 4; ++pass) {
            const int row = pass * 16 + ty;
            const int c4 = tx * 4;
            float4 va = *(const float4*)&A[(size_t)(m0 + row) * PP + k0 + c4];
            As[c4 + 0][row] = va.x; As[c4 + 1][row] = va.y;
            As[c4 + 2][row] = va.z; As[c4 + 3][row] = va.w;
            *(float4*)&Bs[row][c4] =
                *(const float4*)&PM[(size_t)(k0 + row) * (PK + PSD) + PK + n0 + c4];
        }
        __syncthreads();
        #pragma unroll 16
        for (int k = 0; k < 64; ++k) {
            float4 a4 = *(const float4*)&As[k][ty * 4];
            float4 b4 = *(const float4*)&Bs[k][tx * 4];
            float av[4] = {a4.x, a4.y, a4.z, a4.w};
            float bv4[4] = {b4.x, b4.y, b4.z, b4.w};
            #pragma unroll
            for (int i = 0; i < 4; ++i)
                #pragma unroll
                for (int j = 0; j < 4; ++j)
                    acc[i][j] += av[i] * bv4[j];
        }
        __syncthreads();
    }
    #pragma unroll
    for (int i = 0; i < 4; ++i) {
        const int m = m0 + ty * 4 + i;
        const float scale = (comp == 0) ? sbuf[m] : 1.f;
        float4 o = make_float4(acc[i][0] * scale, acc[i][1] * scale,
                               acc[i][2] * scale, acc[i][3] * scale);
        *(float4*)&C[(size_t)m * PSD + n0 + tx * 4] = o;
    }
}

// ---------------------------------------------------------------------------
// Kernel 5: Wrec[b] = (s*Us)[b]^T @ Vs[b].  Per batch: (2048 x 64) @ (64 x 2048).
// grid (256 tiles, 64 b), block 256, 128x128 tile, micro 8x8, K=64 single stage.
// ---------------------------------------------------------------------------
__global__ __launch_bounds__(256) void k_wrec(
    const float* __restrict__ UsS, const float* __restrict__ Vsb,
    float* __restrict__ out)
{
    const int b = blockIdx.y;
    const int ti = blockIdx.x >> 4, tj = blockIdx.x & 15;
    const int i0 = ti * 128, j0 = tj * 128;

    __shared__ float As[64][128];  // [f][i]
    __shared__ float Bs[64][128];  // [f][j]
    const int t = threadIdx.x;

    #pragma unroll
    for (int jj = 0; jj < 8; ++jj) {
        const int idx = jj * 256 + t;       // 0..2047
        const int f = idx >> 5;
        const int c4 = (idx & 31) * 4;
        *(float4*)&As[f][c4] =
            *(const float4*)&UsS[((size_t)b * NFD + f) * PSD + i0 + c4];
        *(float4*)&Bs[f][c4] =
            *(const float4*)&Vsb[((size_t)b * NFD + f) * PSD + j0 + c4];
    }
    __syncthreads();

    const int tx = t & 15, ty = t >> 4;
    const int ib = ty * 8, jb = tx * 8;
    float acc[8][8] = {};

    #pragma unroll 8
    for (int f = 0; f < 64; ++f) {
        float a[8], bb[8];
        *(float4*)&a[0] = *(const float4*)&As[f][ib];
        *(float4*)&a[4] = *(const float4*)&As[f][ib + 4];
        *(float4*)&bb[0] = *(const float4*)&Bs[f][jb];
        *(float4*)&bb[4] = *(const float4*)&Bs[f][jb + 4];
        #pragma unroll
        for (int i = 0; i < 8; ++i)
            #pragma unroll
            for (int j = 0; j < 8; ++j)
                acc[i][j] += a[i] * bb[j];
    }

    float* ob = out + (size_t)b * PSD * PSD;
    #pragma unroll
    for (int i = 0; i < 8; ++i) {
        const size_t ro = (size_t)(i0 + ib + i) * PSD + j0 + jb;
        *(float4*)&ob[ro]     = make_float4(acc[i][0], acc[i][1], acc[i][2], acc[i][3]);
        *(float4*)&ob[ro + 4] = make_float4(acc[i][4], acc[i][5], acc[i][6], acc[i][7]);
    }
}

// ---------------------------------------------------------------------------
extern "C" void kernel_launch(void* const* d_in, const int* in_sizes, int n_in,
                              void* d_out, int out_size, void* d_ws, size_t ws_size,
                              hipStream_t stream)
{
    const float* x   = (const float*)d_in[0];
    const float* PMU = (const float*)d_in[1];
    const float* PMV = (const float*)d_in[2];
    const float* PMS = (const float*)d_in[3];
    const float* Wku = (const float*)d_in[4];
    const float* bku = (const float*)d_in[5];
    const float* Wkv = (const float*)d_in[6];
    const float* bkv = (const float*)d_in[7];
    const float* Wks = (const float*)d_in[8];
    const float* bks = (const float*)d_in[9];
    float* out = (float*)d_out;

    char* ws = (char*)d_ws;
    float* ko   = (float*)(ws);                                // 3 * 64*4096      = 3 MiB
    float* dbuf = (float*)(ws + (size_t)3 * 1024 * 1024);      // 3 * 4096*128     = 6 MiB
    float* a_n  = (float*)(ws + (size_t)9 * 1024 * 1024);      // 3*128
    float* sbuf = a_n + 3 * PP;                                // 4096
    float* UsS  = (float*)(ws + (size_t)16 * 1024 * 1024);     // 4096*2048 = 32 MiB
    float* Vsb  = UsS + (size_t)4096 * PSD;                    // 32 MiB

    k_proj <<<dim3(64, 3),   256, 0, stream>>>(x, Wku, bku, Wkv, bkv, Wks, bks, ko);
    k_norms<<<3,             128, 0, stream>>>(PMU, PMV, PMS, a_n);
    k_theta<<<dim3(4096, 3), 128, 0, stream>>>(ko, PMU, PMV, PMS, a_n, dbuf);
    k_scan <<<64,             64, 0, stream>>>(dbuf, PMS, sbuf);
    k_mp   <<<dim3(32, 64, 2), 256, 0, stream>>>(dbuf, PMU, PMV, sbuf, UsS, Vsb);
    k_wrec <<<dim3(256, 64), 256, 0, stream>>>(UsS, Vsb, out);
}

// Round 2
// 516.566 us; speedup vs baseline: 1.2726x; 1.2726x over previous
//
#include <hip/hip_runtime.h>
#include <math.h>

#define NB 64        // batch
#define IFD 1024     // in features
#define PP 128       // P (num keys)
#define PSD 2048     // PS0/PS1
#define PK 64        // PKEY
#define NFD 64       // NF
#define DELTAF 1e-6f

typedef __bf16 bf16x8 __attribute__((ext_vector_type(8)));
typedef float f32x4 __attribute__((ext_vector_type(4)));

static __device__ __forceinline__ unsigned short f2bf(float f) {
    unsigned int u = __float_as_uint(f);
    u = (u + 0x7FFF + ((u >> 16) & 1)) >> 16;   // RTNE
    return (unsigned short)u;
}

// ---------------------------------------------------------------------------
// Kernel 1: k = x @ W^T + b for 3 components.  C[m][n] = sum_k x[m][k]*W[n][k]
// M=64, N=4096, K=1024.  grid (N/64, 3), block 256, micro 4x4.
// ---------------------------------------------------------------------------
__global__ __launch_bounds__(256) void k_proj(
    const float* __restrict__ x,
    const float* __restrict__ Wu, const float* __restrict__ bu,
    const float* __restrict__ Wv, const float* __restrict__ bv,
    const float* __restrict__ Ws, const float* __restrict__ bs,
    float* __restrict__ ko)   // [3][64][4096]
{
    const int comp = blockIdx.y;
    const float* W    = comp == 0 ? Wu : (comp == 1 ? Wv : Ws);
    const float* bias = comp == 0 ? bu : (comp == 1 ? bv : bs);
    float* out = ko + (size_t)comp * NB * 4096;

    const int n0 = blockIdx.x * 64;
    __shared__ float xs[64][64];   // [k][m]
    __shared__ float ws_t[64][64]; // [k][n]
    const int t = threadIdx.x;
    const int tx = t & 15, ty = t >> 4;

    float acc[4][4] = {};

    for (int k0 = 0; k0 < IFD; k0 += 64) {
        #pragma unroll
        for (int pass = 0; pass < 4; ++pass) {
            const int row = pass * 16 + ty;
            const int c4 = tx * 4;
            float4 va = *(const float4*)&x[(size_t)row * IFD + k0 + c4];
            xs[c4 + 0][row] = va.x; xs[c4 + 1][row] = va.y;
            xs[c4 + 2][row] = va.z; xs[c4 + 3][row] = va.w;
            float4 vb = *(const float4*)&W[(size_t)(n0 + row) * IFD + k0 + c4];
            ws_t[c4 + 0][row] = vb.x; ws_t[c4 + 1][row] = vb.y;
            ws_t[c4 + 2][row] = vb.z; ws_t[c4 + 3][row] = vb.w;
        }
        __syncthreads();
        #pragma unroll 16
        for (int k = 0; k < 64; ++k) {
            float4 a4 = *(const float4*)&xs[k][ty * 4];
            float4 b4 = *(const float4*)&ws_t[k][tx * 4];
            float av[4] = {a4.x, a4.y, a4.z, a4.w};
            float bv4[4] = {b4.x, b4.y, b4.z, b4.w};
            #pragma unroll
            for (int i = 0; i < 4; ++i)
                #pragma unroll
                for (int j = 0; j < 4; ++j)
                    acc[i][j] += av[i] * bv4[j];
        }
        __syncthreads();
    }
    #pragma unroll
    for (int i = 0; i < 4; ++i) {
        const int m = ty * 4 + i;
        const int n = n0 + tx * 4;
        float4 o = make_float4(acc[i][0] + bias[n + 0], acc[i][1] + bias[n + 1],
                               acc[i][2] + bias[n + 2], acc[i][3] + bias[n + 3]);
        *(float4*)&out[(size_t)m * 4096 + n] = o;
    }
}

// ---------------------------------------------------------------------------
// Kernel 2a: a_n[comp][p] = ||MK_p|| + DELTA.  grid 3, block 128.
// ---------------------------------------------------------------------------
__global__ void k_norms(const float* __restrict__ PMU, const float* __restrict__ PMV,
                        const float* __restrict__ PMS, float* __restrict__ a_n)
{
    const int comp = blockIdx.x;
    const float* PM = comp == 0 ? PMU : (comp == 1 ? PMV : PMS);
    const int stride = (comp == 2) ? (PK + 1) : (PK + PSD);
    const int p = threadIdx.x;
    const float* row = PM + (size_t)p * stride;
    float ss = 0.f;
    #pragma unroll
    for (int k = 0; k < PK; ++k) { float v = row[k]; ss += v * v; }
    a_n[comp * PP + p] = sqrtf(ss) + DELTAF;
}

// ---------------------------------------------------------------------------
// Kernel 2b: theta + softmax.  grid (B*NF, 3), block 128 (one thread per p).
// ---------------------------------------------------------------------------
__global__ __launch_bounds__(128) void k_theta(
    const float* __restrict__ ko, const float* __restrict__ PMU,
    const float* __restrict__ PMV, const float* __restrict__ PMS,
    const float* __restrict__ a_n, float* __restrict__ dout)  // [3][4096][128]
{
    const int comp = blockIdx.y;
    const float* PM = comp == 0 ? PMU : (comp == 1 ? PMV : PMS);
    const int stride = (comp == 2) ? (PK + 1) : (PK + PSD);
    const float* krow = ko + (size_t)comp * NB * 4096 + (size_t)blockIdx.x * PK;
    float* drow = dout + (size_t)comp * 4096 * PP + (size_t)blockIdx.x * PP;

    __shared__ float kr[PK];
    __shared__ float mk[PP][PK + 1];
    __shared__ float smax[2], ssum[2];

    const int t = threadIdx.x;
    if (t < PK) kr[t] = krow[t];
    for (int idx = t; idx < PP * PK; idx += 128) {
        const int r = idx >> 6, c = idx & 63;
        mk[r][c] = PM[(size_t)r * stride + c];
    }
    __syncthreads();

    float ss = 0.f;
    #pragma unroll
    for (int k = 0; k < PK; ++k) ss += kr[k] * kr[k];
    const float b_n = sqrtf(ss) + DELTAF;

    const int p = t;
    float num = 0.f;
    #pragma unroll
    for (int k = 0; k < PK; ++k) num += mk[p][k] * kr[k];
    const float dval = num / (64.f * b_n * a_n[comp * PP + p] + DELTAF);

    float mx = dval;
    #pragma unroll
    for (int o = 32; o >= 1; o >>= 1) mx = fmaxf(mx, __shfl_xor(mx, o, 64));
    if ((t & 63) == 0) smax[t >> 6] = mx;
    __syncthreads();
    mx = fmaxf(smax[0], smax[1]);
    const float e = expf(dval - mx);
    float sm = e;
    #pragma unroll
    for (int o = 32; o >= 1; o >>= 1) sm += __shfl_xor(sm, o, 64);
    if ((t & 63) == 0) ssum[t >> 6] = sm;
    __syncthreads();
    sm = ssum[0] + ssum[1];
    drow[p] = e / sm;
}

// ---------------------------------------------------------------------------
// Kernel 3: s[b,f] = cumsum_f( softplus( d_s[b,f,:] . MP_S ) ).  grid 64, block 64.
// ---------------------------------------------------------------------------
__global__ void k_scan(const float* __restrict__ dout, const float* __restrict__ PMS,
                       float* __restrict__ sbuf)
{
    const int b = blockIdx.x, f = threadIdx.x;
    __shared__ float mp[PP];
    mp[f] = PMS[(size_t)f * (PK + 1) + PK];
    mp[f + 64] = PMS[(size_t)(f + 64) * (PK + 1) + PK];
    __syncthreads();
    const float* drow = dout + (size_t)2 * 4096 * PP + ((size_t)b * NFD + f) * PP;
    float v = 0.f;
    #pragma unroll
    for (int p = 0; p < PP; ++p) v += drow[p] * mp[p];
    float sp = (v > 20.f) ? v : log1pf(expf(v));
    #pragma unroll
    for (int o = 1; o < 64; o <<= 1) {
        float u = __shfl_up(sp, o, 64);
        if (f >= o) sp += u;
    }
    sbuf[b * NFD + f] = sp;
}

// ---------------------------------------------------------------------------
// Kernel 4: Us/Vs = d @ MP  (M=4096, K=128, N=2048); U scaled by s[m].
// Epilogue: write bf16 TRANSPOSED per batch: T[b][n][f]  (b = m>>6, f = m&63).
// grid (32, 64, 2), block 256, micro 4x4, BK=64.  One block = one batch's f's.
// ---------------------------------------------------------------------------
__global__ __launch_bounds__(256) void k_mp(
    const float* __restrict__ dout, const float* __restrict__ PMU,
    const float* __restrict__ PMV, const float* __restrict__ sbuf,
    unsigned short* __restrict__ UsT, unsigned short* __restrict__ VsT)
{
    const int comp = blockIdx.z;
    const float* A = dout + (size_t)comp * 4096 * PP;
    const float* PM = comp == 0 ? PMU : PMV;
    unsigned short* CT = comp == 0 ? UsT : VsT;
    const int n0 = blockIdx.x * 64, m0 = blockIdx.y * 64;
    const int batch = blockIdx.y;          // m0 = batch*64, f = m - m0

    __shared__ float As[64][64];  // [k][m]
    __shared__ float Bs[64][64];  // [k][n]
    __shared__ unsigned short sT[64][72];  // [n_local][f], padded
    const int t = threadIdx.x, tx = t & 15, ty = t >> 4;
    float acc[4][4] = {};

    for (int k0 = 0; k0 < PP; k0 += 64) {
        #pragma unroll
        for (int pass = 0; pass < 4; ++pass) {
            const int row = pass * 16 + ty;
            const int c4 = tx * 4;
            float4 va = *(const float4*)&A[(size_t)(m0 + row) * PP + k0 + c4];
            As[c4 + 0][row] = va.x; As[c4 + 1][row] = va.y;
            As[c4 + 2][row] = va.z; As[c4 + 3][row] = va.w;
            *(float4*)&Bs[row][c4] =
                *(const float4*)&PM[(size_t)(k0 + row) * (PK + PSD) + PK + n0 + c4];
        }
        __syncthreads();
        #pragma unroll 16
        for (int k = 0; k < 64; ++k) {
            float4 a4 = *(const float4*)&As[k][ty * 4];
            float4 b4 = *(const float4*)&Bs[k][tx * 4];
            float av[4] = {a4.x, a4.y, a4.z, a4.w};
            float bv4[4] = {b4.x, b4.y, b4.z, b4.w};
            #pragma unroll
            for (int i = 0; i < 4; ++i)
                #pragma unroll
                for (int j = 0; j < 4; ++j)
                    acc[i][j] += av[i] * bv4[j];
        }
        __syncthreads();
    }

    // transpose tile into LDS as bf16: sT[n_local][f]
    #pragma unroll
    for (int i = 0; i < 4; ++i) {
        const int m = m0 + ty * 4 + i;
        const float scale = (comp == 0) ? sbuf[m] : 1.f;
        #pragma unroll
        for (int j = 0; j < 4; ++j)
            sT[tx * 4 + j][ty * 4 + i] = f2bf(acc[i][j] * scale);
    }
    __syncthreads();

    // packed stores: 64 rows x 128B; 256 threads -> each stores 32B (16 bf16)
    {
        const int r = t >> 2;            // 0..63  (n_local)
        const int c = (t & 3) * 16;      // f chunk
        unsigned short* dst = CT + (size_t)batch * PSD * NFD + (size_t)(n0 + r) * NFD + c;
        *(float4*)&dst[0] = *(const float4*)&sT[r][c];
        *(float4*)&dst[8] = *(const float4*)&sT[r][c + 8];
    }
}

// ---------------------------------------------------------------------------
// Kernel 5 (MFMA): Wrec[b] = UsS[b]^T @ Vs[b] via bf16 16x16x32 MFMA.
// Operands: UsT/VsT [b][2048][64] bf16 row-major along f.  No LDS.
// grid (256 tiles of 128x128, 64 b), block 256 = 4 waves (2x2 of 64x64).
// ---------------------------------------------------------------------------
__global__ __launch_bounds__(256) void k_wrec(
    const unsigned short* __restrict__ UsT, const unsigned short* __restrict__ VsT,
    float* __restrict__ out)
{
    const int b = blockIdx.y;
    const int ti = blockIdx.x >> 4, tj = blockIdx.x & 15;
    const int i0 = ti * 128, j0 = tj * 128;
    const int w = threadIdx.x >> 6, l = threadIdx.x & 63;
    const int wr = w >> 1, wc = w & 1;
    const int lr = l & 15, lk = (l >> 4) * 8;

    const unsigned short* A = UsT + (size_t)b * PSD * NFD;
    const unsigned short* B = VsT + (size_t)b * PSD * NFD;

    bf16x8 af[2][4], bf[2][4];
    #pragma unroll
    for (int kk = 0; kk < 2; ++kk)
        #pragma unroll
        for (int fi = 0; fi < 4; ++fi) {
            af[kk][fi] = *(const bf16x8*)&A[(size_t)(i0 + wr * 64 + fi * 16 + lr) * NFD + kk * 32 + lk];
            bf[kk][fi] = *(const bf16x8*)&B[(size_t)(j0 + wc * 64 + fi * 16 + lr) * NFD + kk * 32 + lk];
        }

    f32x4 acc[4][4] = {};
    #pragma unroll
    for (int kk = 0; kk < 2; ++kk)
        #pragma unroll
        for (int fi = 0; fi < 4; ++fi)
            #pragma unroll
            for (int fj = 0; fj < 4; ++fj)
                acc[fi][fj] = __builtin_amdgcn_mfma_f32_16x16x32_bf16(
                    af[kk][fi], bf[kk][fj], acc[fi][fj], 0, 0, 0);

    float* ob = out + (size_t)b * (size_t)PSD * PSD;
    const int rbase = (l >> 4) * 4, cl = l & 15;
    #pragma unroll
    for (int fi = 0; fi < 4; ++fi) {
        #pragma unroll
        for (int r = 0; r < 4; ++r) {
            const size_t row = (size_t)(i0 + wr * 64 + fi * 16 + rbase + r) * PSD;
            #pragma unroll
            for (int fj = 0; fj < 4; ++fj)
                ob[row + j0 + wc * 64 + fj * 16 + cl] = acc[fi][fj][r];
        }
    }
}

// ---------------------------------------------------------------------------
extern "C" void kernel_launch(void* const* d_in, const int* in_sizes, int n_in,
                              void* d_out, int out_size, void* d_ws, size_t ws_size,
                              hipStream_t stream)
{
    const float* x   = (const float*)d_in[0];
    const float* PMU = (const float*)d_in[1];
    const float* PMV = (const float*)d_in[2];
    const float* PMS = (const float*)d_in[3];
    const float* Wku = (const float*)d_in[4];
    const float* bku = (const float*)d_in[5];
    const float* Wkv = (const float*)d_in[6];
    const float* bkv = (const float*)d_in[7];
    const float* Wks = (const float*)d_in[8];
    const float* bks = (const float*)d_in[9];
    float* out = (float*)d_out;

    char* ws = (char*)d_ws;
    float* ko   = (float*)(ws);                                // 3 MiB
    float* dbuf = (float*)(ws + (size_t)3 * 1024 * 1024);      // 6 MiB
    float* a_n  = (float*)(ws + (size_t)9 * 1024 * 1024);
    float* sbuf = a_n + 3 * PP;
    unsigned short* UsT = (unsigned short*)(ws + (size_t)16 * 1024 * 1024); // 16 MiB
    unsigned short* VsT = (unsigned short*)(ws + (size_t)32 * 1024 * 1024); // 16 MiB

    k_proj <<<dim3(64, 3),   256, 0, stream>>>(x, Wku, bku, Wkv, bkv, Wks, bks, ko);
    k_norms<<<3,             128, 0, stream>>>(PMU, PMV, PMS, a_n);
    k_theta<<<dim3(4096, 3), 128, 0, stream>>>(ko, PMU, PMV, PMS, a_n, dbuf);
    k_scan <<<64,             64, 0, stream>>>(dbuf, PMS, sbuf);
    k_mp   <<<dim3(32, 64, 2), 256, 0, stream>>>(dbuf, PMU, PMV, sbuf, UsT, VsT);
    k_wrec <<<dim3(256, 64), 256, 0, stream>>>(UsT, VsT, out);
}

// Round 3
// 376.068 us; speedup vs baseline: 1.7480x; 1.3736x over previous
//
#include <hip/hip_runtime.h>
#include <math.h>

#define NB 64        // batch
#define IFD 1024     // in features
#define PP 128       // P (num keys)
#define PSD 2048     // PS0/PS1
#define PK 64        // PKEY
#define NFD 64       // NF
#define DELTAF 1e-6f

typedef __bf16 bf16x8 __attribute__((ext_vector_type(8)));
typedef float f32x4 __attribute__((ext_vector_type(4)));
typedef unsigned short ushort;

static __device__ __forceinline__ ushort f2bf(float f) {
    unsigned int u = __float_as_uint(f);
    u = (u + 0x7FFF + ((u >> 16) & 1)) >> 16;   // RTNE
    return (ushort)u;
}
static __device__ __forceinline__ unsigned int pack2bf(float a, float b) {
    return (unsigned int)f2bf(a) | ((unsigned int)f2bf(b) << 16);
}
// load 8 fp32 (any 4B-aligned addr) -> bf16x8 fragment
static __device__ __forceinline__ bf16x8 ld8cvt(const float* p) {
    float a[8];
    __builtin_memcpy(a, p, 32);
    bf16x8 r;
    #pragma unroll
    for (int i = 0; i < 8; ++i) r[i] = (__bf16)a[i];
    return r;
}

// ---------------------------------------------------------------------------
// Kernel 1 (MFMA): ko[comp][m][n] = sum_k x[m][k] * W[n][k] + b[n]
// M=64, N=4096, K=1024.  grid (64 n-tiles, 3), block 64 (1 wave, 64m x 64n).
// Both x and W are [row][k] row-major -> direct A/B fragments, cvt in flight.
// ---------------------------------------------------------------------------
__global__ __launch_bounds__(64) void k_proj(
    const float* __restrict__ x,
    const float* __restrict__ Wu, const float* __restrict__ bu,
    const float* __restrict__ Wv, const float* __restrict__ bv,
    const float* __restrict__ Ws, const float* __restrict__ bs,
    float* __restrict__ ko)
{
    const int comp = blockIdx.y;
    const float* W    = comp == 0 ? Wu : (comp == 1 ? Wv : Ws);
    const float* bias = comp == 0 ? bu : (comp == 1 ? bv : bs);
    float* out = ko + (size_t)comp * NB * 4096;

    const int n0 = blockIdx.x * 64;
    const int l = threadIdx.x;
    const int lr = l & 15, lk8 = (l >> 4) * 8;

    f32x4 acc[4][4] = {};
    #pragma unroll 2
    for (int kk = 0; kk < IFD; kk += 32) {
        bf16x8 af[4], bw[4];
        #pragma unroll
        for (int fi = 0; fi < 4; ++fi)
            af[fi] = ld8cvt(&x[(size_t)(fi * 16 + lr) * IFD + kk + lk8]);
        #pragma unroll
        for (int fj = 0; fj < 4; ++fj)
            bw[fj] = ld8cvt(&W[(size_t)(n0 + fj * 16 + lr) * IFD + kk + lk8]);
        #pragma unroll
        for (int fi = 0; fi < 4; ++fi)
            #pragma unroll
            for (int fj = 0; fj < 4; ++fj)
                acc[fi][fj] = __builtin_amdgcn_mfma_f32_16x16x32_bf16(
                    af[fi], bw[fj], acc[fi][fj], 0, 0, 0);
    }
    const int rb = (l >> 4) * 4, cl = l & 15;
    #pragma unroll
    for (int fi = 0; fi < 4; ++fi)
        #pragma unroll
        for (int fj = 0; fj < 4; ++fj) {
            const int n = n0 + fj * 16 + cl;
            const float bv_ = bias[n];
            #pragma unroll
            for (int r = 0; r < 4; ++r)
                out[(size_t)(fi * 16 + rb + r) * 4096 + n] = acc[fi][fj][r] + bv_;
        }
}

// ---------------------------------------------------------------------------
// Kernel 2a: a_n[comp][p] = ||MK_p|| + DELTA.
// ---------------------------------------------------------------------------
__global__ void k_norms(const float* __restrict__ PMU, const float* __restrict__ PMV,
                        const float* __restrict__ PMS, float* __restrict__ a_n)
{
    const int comp = blockIdx.x;
    const float* PM = comp == 0 ? PMU : (comp == 1 ? PMV : PMS);
    const int stride = (comp == 2) ? (PK + 1) : (PK + PSD);
    const int p = threadIdx.x;
    const float* row = PM + (size_t)p * stride;
    float ss = 0.f;
    #pragma unroll
    for (int k = 0; k < PK; ++k) { float v = row[k]; ss += v * v; }
    a_n[comp * PP + p] = sqrtf(ss) + DELTAF;
}

// ---------------------------------------------------------------------------
// Kernel 2b (MFMA): theta + softmax (+ fused softplus-cumsum for comp 2).
// Per block: one (batch g, comp): C[64 f][128 p] = krs @ mk^T via MFMA.
// block 256 = 4 waves, wave w owns rows w*16..+15 (fi=1, fj=8, kk=2).
// Softmax over p is in-register (fj) + 16-lane shfl — no cross-wave sync.
// comp<2 -> write d16 bf16 [comp][m][p]; comp==2 -> v=d.mpS, scan -> sbuf.
// ---------------------------------------------------------------------------
__global__ __launch_bounds__(256) void k_theta(
    const float* __restrict__ ko,
    const float* __restrict__ PMU, const float* __restrict__ PMV,
    const float* __restrict__ PMS, const float* __restrict__ a_n,
    ushort* __restrict__ d16, float* __restrict__ sbuf)
{
    const int comp = blockIdx.y;
    const int g = blockIdx.x;            // batch
    const float* PM = comp == 0 ? PMU : (comp == 1 ? PMV : PMS);
    const int stride = (comp == 2) ? (PK + 1) : (PK + PSD);
    const float* kg = ko + ((size_t)comp * NB + g) * 4096;

    __shared__ float an_s[128], bn_s[64], mpS[128], vrow[64];
    const int t = threadIdx.x;
    if (t < 128) an_s[t] = a_n[comp * PP + t];
    if (t < 64) {
        float ss = 0.f;
        #pragma unroll
        for (int k = 0; k < PK; ++k) { float v = kg[t * PK + k]; ss += v * v; }
        bn_s[t] = sqrtf(ss) + DELTAF;
    }
    if (comp == 2 && t >= 128) mpS[t - 128] = PM[(size_t)(t - 128) * stride + PK];
    __syncthreads();

    const int w = t >> 6, l = t & 63;
    const int lr = l & 15, lk8 = (l >> 4) * 8;

    f32x4 acc[8] = {};
    #pragma unroll
    for (int kk = 0; kk < 2; ++kk) {
        bf16x8 af = ld8cvt(&kg[(size_t)(w * 16 + lr) * PK + kk * 32 + lk8]);
        #pragma unroll
        for (int fj = 0; fj < 8; ++fj) {
            bf16x8 bw = ld8cvt(&PM[(size_t)(fj * 16 + lr) * stride + kk * 32 + lk8]);
            acc[fj] = __builtin_amdgcn_mfma_f32_16x16x32_bf16(af, bw, acc[fj], 0, 0, 0);
        }
    }

    const int rb = (l >> 4) * 4, cl = l & 15;
    float dv[8][4];
    #pragma unroll
    for (int fj = 0; fj < 8; ++fj) {
        const float an_v = an_s[fj * 16 + cl];
        #pragma unroll
        for (int r = 0; r < 4; ++r)
            dv[fj][r] = acc[fj][r] / (64.f * bn_s[w * 16 + rb + r] * an_v + DELTAF);
    }
    // softmax over p: in-register over fj, then 16-lane butterfly
    #pragma unroll
    for (int r = 0; r < 4; ++r) {
        float m = dv[0][r];
        #pragma unroll
        for (int fj = 1; fj < 8; ++fj) m = fmaxf(m, dv[fj][r]);
        #pragma unroll
        for (int msk = 1; msk < 16; msk <<= 1) m = fmaxf(m, __shfl_xor(m, msk, 64));
        float s = 0.f;
        #pragma unroll
        for (int fj = 0; fj < 8; ++fj) { dv[fj][r] = expf(dv[fj][r] - m); s += dv[fj][r]; }
        #pragma unroll
        for (int msk = 1; msk < 16; msk <<= 1) s += __shfl_xor(s, msk, 64);
        const float inv = 1.f / s;
        #pragma unroll
        for (int fj = 0; fj < 8; ++fj) dv[fj][r] *= inv;
    }

    if (comp < 2) {
        ushort* drow = d16 + ((size_t)comp * 4096 + g * 64) * PP;
        #pragma unroll
        for (int fj = 0; fj < 8; ++fj)
            #pragma unroll
            for (int r = 0; r < 4; ++r)
                drow[(size_t)(w * 16 + rb + r) * PP + fj * 16 + cl] = f2bf(dv[fj][r]);
    } else {
        #pragma unroll
        for (int r = 0; r < 4; ++r) {
            float v = 0.f;
            #pragma unroll
            for (int fj = 0; fj < 8; ++fj) v += dv[fj][r] * mpS[fj * 16 + cl];
            #pragma unroll
            for (int msk = 1; msk < 16; msk <<= 1) v += __shfl_xor(v, msk, 64);
            if ((l & 15) == 0) vrow[w * 16 + rb + r] = v;
        }
        __syncthreads();
        if (t < 64) {
            float v = vrow[t];
            float sp = (v > 20.f) ? v : log1pf(expf(v));
            #pragma unroll
            for (int o = 1; o < 64; o <<= 1) {
                float u = __shfl_up(sp, o, 64);
                if (t >= o) sp += u;
            }
            sbuf[g * 64 + t] = sp;
        }
    }
}

// ---------------------------------------------------------------------------
// Kernel 3: transpose MP[:,PK:] -> MPt[comp][n][p] bf16.  grid (32, 2), blk 256.
// ---------------------------------------------------------------------------
__global__ __launch_bounds__(256) void k_mpt(
    const float* __restrict__ PMU, const float* __restrict__ PMV,
    ushort* __restrict__ MPt)
{
    const int comp = blockIdx.y;
    const float* PM = comp == 0 ? PMU : PMV;
    ushort* dst = MPt + (size_t)comp * PSD * PP;
    const int n0 = blockIdx.x * 64;
    __shared__ ushort Tl[64][136];
    const int t = threadIdx.x;
    const int nl = t & 63, p4 = t >> 6;
    #pragma unroll
    for (int it = 0; it < 32; ++it) {
        const int p = it * 4 + p4;
        Tl[nl][p] = f2bf(PM[(size_t)p * (PK + PSD) + PK + n0 + nl]);
    }
    __syncthreads();
    const int r = t >> 2, c = (t & 3) * 32;
    #pragma unroll
    for (int j = 0; j < 32; j += 8)
        *(f32x4*)&dst[(size_t)(n0 + r) * PP + c + j] = *(const f32x4*)&Tl[r][c + j];
}

// ---------------------------------------------------------------------------
// Kernel 4 (MFMA): Us/Vs = d16 @ MPt^T; Us scaled by s; output bf16 [b][n][f].
// M=4096, N=2048, K=128.  grid (16, 32, 2), block 256 (2x2 waves, 64x64 each).
// ---------------------------------------------------------------------------
__global__ __launch_bounds__(256) void k_mp(
    const ushort* __restrict__ d16, const ushort* __restrict__ MPt,
    const float* __restrict__ sbuf,
    ushort* __restrict__ UsT, ushort* __restrict__ VsT)
{
    const int comp = blockIdx.z;
    const ushort* A = d16 + (size_t)comp * 4096 * PP;
    const ushort* B = MPt + (size_t)comp * PSD * PP;
    ushort* C = comp == 0 ? UsT : VsT;
    const int n0 = blockIdx.x * 128, m0 = blockIdx.y * 128;
    const int w = threadIdx.x >> 6, l = threadIdx.x & 63;
    const int wr = w >> 1, wc = w & 1;
    const int lr = l & 15, lk8 = (l >> 4) * 8;

    f32x4 acc[4][4] = {};
    #pragma unroll
    for (int kk = 0; kk < 4; ++kk) {
        bf16x8 af[4], bw[4];
        #pragma unroll
        for (int fi = 0; fi < 4; ++fi)
            af[fi] = *(const bf16x8*)&A[(size_t)(m0 + wr * 64 + fi * 16 + lr) * PP + kk * 32 + lk8];
        #pragma unroll
        for (int fj = 0; fj < 4; ++fj)
            bw[fj] = *(const bf16x8*)&B[(size_t)(n0 + wc * 64 + fj * 16 + lr) * PP + kk * 32 + lk8];
        #pragma unroll
        for (int fi = 0; fi < 4; ++fi)
            #pragma unroll
            for (int fj = 0; fj < 4; ++fj)
                acc[fi][fj] = __builtin_amdgcn_mfma_f32_16x16x32_bf16(
                    af[fi], bw[fj], acc[fi][fj], 0, 0, 0);
    }

    const int batch = (m0 >> 6) + wr;
    const int rb = (l >> 4) * 4, cl = l & 15;
    ushort* Cb = C + (size_t)batch * PSD * NFD;
    #pragma unroll
    for (int fi = 0; fi < 4; ++fi) {
        const int f0 = fi * 16 + rb;
        f32x4 sc;
        if (comp == 0) sc = *(const f32x4*)&sbuf[batch * 64 + f0];
        else           sc = (f32x4){1.f, 1.f, 1.f, 1.f};
        #pragma unroll
        for (int fj = 0; fj < 4; ++fj) {
            const int n = n0 + wc * 64 + fj * 16 + cl;
            uint2 pk;
            pk.x = pack2bf(acc[fi][fj][0] * sc[0], acc[fi][fj][1] * sc[1]);
            pk.y = pack2bf(acc[fi][fj][2] * sc[2], acc[fi][fj][3] * sc[3]);
            *(uint2*)&Cb[(size_t)n * NFD + f0] = pk;
        }
    }
}

// ---------------------------------------------------------------------------
// Kernel 5 (MFMA): Wrec[b] = Us[b]^T @ Vs[b].  Tile = 16 rows x FULL 2048 cols
// -> each block writes one CONTIGUOUS 128 KB span (HBM row locality).
// grid (128, 64), block 512 = 8 waves; wave w = cols [w*256, +256), fj=16.
// ---------------------------------------------------------------------------
__global__ __launch_bounds__(512) void k_wrec(
    const ushort* __restrict__ UsT, const ushort* __restrict__ VsT,
    float* __restrict__ out)
{
    const int b = blockIdx.y;
    const int i0 = blockIdx.x * 16;
    const int w = threadIdx.x >> 6, l = threadIdx.x & 63;
    const int j0 = w * 256;
    const int lr = l & 15, lk8 = (l >> 4) * 8;
    const ushort* A  = UsT + (size_t)b * PSD * NFD;
    const ushort* Bp = VsT + (size_t)b * PSD * NFD;

    f32x4 acc[16] = {};
    #pragma unroll
    for (int kk = 0; kk < 2; ++kk) {
        bf16x8 af = *(const bf16x8*)&A[(size_t)(i0 + lr) * NFD + kk * 32 + lk8];
        #pragma unroll
        for (int fj = 0; fj < 16; ++fj) {
            bf16x8 bw = *(const bf16x8*)&Bp[(size_t)(j0 + fj * 16 + lr) * NFD + kk * 32 + lk8];
            acc[fj] = __builtin_amdgcn_mfma_f32_16x16x32_bf16(af, bw, acc[fj], 0, 0, 0);
        }
    }
    const int rb = (l >> 4) * 4, cl = l & 15;
    float* ob = out + (size_t)b * (size_t)PSD * PSD;
    #pragma unroll
    for (int r = 0; r < 4; ++r) {
        const size_t row = (size_t)(i0 + rb + r) * PSD;
        #pragma unroll
        for (int fj = 0; fj < 16; ++fj)
            __builtin_nontemporal_store(acc[fj][r], &ob[row + j0 + fj * 16 + cl]);
    }
}

// ---------------------------------------------------------------------------
extern "C" void kernel_launch(void* const* d_in, const int* in_sizes, int n_in,
                              void* d_out, int out_size, void* d_ws, size_t ws_size,
                              hipStream_t stream)
{
    const float* x   = (const float*)d_in[0];
    const float* PMU = (const float*)d_in[1];
    const float* PMV = (const float*)d_in[2];
    const float* PMS = (const float*)d_in[3];
    const float* Wku = (const float*)d_in[4];
    const float* bku = (const float*)d_in[5];
    const float* Wkv = (const float*)d_in[6];
    const float* bkv = (const float*)d_in[7];
    const float* Wks = (const float*)d_in[8];
    const float* bks = (const float*)d_in[9];
    float* out = (float*)d_out;

    char* ws = (char*)d_ws;
    float*  ko   = (float*)(ws);                                 // 3 MiB
    ushort* d16  = (ushort*)(ws + (size_t)3 * 1024 * 1024);      // 2 MiB
    ushort* MPt  = (ushort*)(ws + (size_t)5 * 1024 * 1024);      // 1 MiB
    float*  sbuf = (float*)(ws + (size_t)6 * 1024 * 1024);       // 16 KiB
    float*  a_n  = (float*)(ws + (size_t)6 * 1024 * 1024 + 65536);
    ushort* UsT  = (ushort*)(ws + (size_t)8 * 1024 * 1024);      // 16 MiB
    ushort* VsT  = (ushort*)(ws + (size_t)24 * 1024 * 1024);     // 16 MiB

    k_proj <<<dim3(64, 3),     64, 0, stream>>>(x, Wku, bku, Wkv, bkv, Wks, bks, ko);
    k_norms<<<3,              128, 0, stream>>>(PMU, PMV, PMS, a_n);
    k_mpt  <<<dim3(32, 2),    256, 0, stream>>>(PMU, PMV, MPt);
    k_theta<<<dim3(64, 3),    256, 0, stream>>>(ko, PMU, PMV, PMS, a_n, d16, sbuf);
    k_mp   <<<dim3(16, 32, 2),256, 0, stream>>>(d16, MPt, sbuf, UsT, VsT);
    k_wrec <<<dim3(128, 64),  512, 0, stream>>>(UsT, VsT, out);
}